// Round 11
// baseline (167.409 us; speedup 1.0000x reference)
//
#include <hip/hip_runtime.h>

// Problem constants (from reference setup_inputs):
//   image:  (B=4, H=512, W=640, C=16) fp32   (83.9 MB)
//   depth:  (B, H, W) fp32                    (5.2 MB)
//   proj:   (B, 4, 4) fp32
//   out:    (B, H, W, C) fp32                 (83.9 MB)
constexpr int B  = 4;
constexpr int H  = 512;
constexpr int Wd = 640;
constexpr int NPIX_IMG = H * Wd;
constexpr int BLOCK = 256;
constexpr int ROWS  = B * H;            // 2048 rows total
constexpr int GRID  = ROWS;             // one block per image row (all co-resident)
constexpr int CHUNK = 64;               // pixels per iteration (256 threads / 4 c4)
constexpr int NCH   = Wd / CHUNK;       // 10 iterations per row
static_assert(NCH * CHUNK == Wd, "chunks tile the row exactly");
static_assert(ROWS % 8 == 0, "XCD swizzle needs rows % 8 == 0");

// Native vector type for nontemporal builtins (HIP_vector_type is rejected).
typedef float f32x4 __attribute__((ext_vector_type(4)));

// Round-9 theory: all short-lived-wave structures pin at ~2.9 TB/s. The 6.3
// TB/s copy differs in ONE property: long-lived waves with continuously
// outstanding sequential loads. This kernel gives each wave that profile:
// one block owns one image row, walks it in 10 chunks with a register
// double-buffer (prefetch chunk n+1 issued AFTER chunk n's gathers so
// in-order vmcnt never stalls on the prefetch; consumed one iteration later
// when complete). Gather lines are warmed into the SAME XCD's L2 by this
// block / the row+1 neighbor block via the row swizzle (blk&7)*256+(blk>>3)
// (round-robin dispatch -> consecutive rows on one XCD). Warming is a perf
// hint only; the gathers themselves guarantee correctness.
__global__ __launch_bounds__(256) void depth_project_kernel(
    const float* __restrict__ image,
    const float* __restrict__ depth,
    const float* __restrict__ proj,
    float4* __restrict__ out)
{
    const int blk = blockIdx.x;
    const int tix = threadIdx.x;

    // XCD-contiguous row assignment (8 XCDs, round-robin block dispatch):
    // XCD x owns rows [x*256, (x+1)*256) in resident order.
    const int row = (blk & 7) * (ROWS / 8) + (blk >> 3);
    const int b   = row / H;
    const int h   = row % H;

    const int c4 = tix & 3;             // float4 group of the 16 channels
    const int pl = tix >> 2;            // pixel within chunk (0..63)
    const int rowpix = row * Wd;        // == (b*H + h)*Wd

    const float* P = proj + b * 16;     // block-uniform -> scalar loads
    const float y = (float)h;

    const f32x4*  img_v = (const f32x4*)image;
    const float4* img4  = (const float4*)image;
    const int ibase = b * (NPIX_IMG * 4);   // float4 units
    f32x4* out_v = (f32x4*)out;

    // ---- prologue: chunk 0 depth + image prefetch ----
    float d_cur = depth[rowpix + pl];
    f32x4 pf = img_v[rowpix * 4 + tix];     // chunk 0 image (4 KB/block)

    for (int n = 0; n < NCH; ++n) {
        const int px = n * CHUNK + pl;      // x of this thread's pixel
        const float x = (float)px;

        // consume previous prefetch (issued >=1 iteration ago -> wait ~free)
        asm volatile("" :: "v"(pf.x), "v"(pf.y), "v"(pf.z), "v"(pf.w));

        // coords / weights (pure VALU on d_cur)
        float sx = (P[0] * x + P[1] * y + P[2])  * d_cur + P[3];
        float sy = (P[4] * x + P[5] * y + P[6])  * d_cur + P[7];
        float sz = (P[8] * x + P[9] * y + P[10]) * d_cur + P[11];
        float cx = sx / sz;
        float cy = sy / sz;

        float x0f = floorf(cx), y0f = floorf(cy);
        float wx1 = cx - x0f,   wy1 = cy - y0f;
        float wx0 = 1.0f - wx1, wy0 = 1.0f - wy1;
        int x0 = (int)x0f, y0 = (int)y0f;
        int x1 = x0 + 1,   y1 = y0 + 1;

        float vx0 = (x0 >= 0 && x0 < Wd) ? 1.0f : 0.0f;
        float vx1 = (x1 >= 0 && x1 < Wd) ? 1.0f : 0.0f;
        float vy0 = (y0 >= 0 && y0 < H)  ? 1.0f : 0.0f;
        float vy1 = (y1 >= 0 && y1 < H)  ? 1.0f : 0.0f;

        int x0c = min(max(x0, 0), Wd - 1);
        int x1c = min(max(x1, 0), Wd - 1);
        int y0c = min(max(y0, 0), H - 1);
        int y1c = min(max(y1, 0), H - 1);

        float w00 = wy0 * wx0 * vy0 * vx0;
        float w01 = wy0 * wx1 * vy0 * vx1;
        float w10 = wy1 * wx0 * vy1 * vx0;
        float w11 = wy1 * wx1 * vy1 * vx1;

        // gathers for chunk n (lines warmed ~2.7us ago by self/neighbor row)
        float4 g00 = img4[ibase + (y0c * Wd + x0c) * 4 + c4];
        float4 g01 = img4[ibase + (y0c * Wd + x1c) * 4 + c4];
        float4 g10 = img4[ibase + (y1c * Wd + x0c) * 4 + c4];
        float4 g11 = img4[ibase + (y1c * Wd + x1c) * 4 + c4];

        // prefetch chunk n+1 AFTER the gathers: the gather wait (in-order
        // vmcnt) then never waits on the prefetch; pf stays in flight
        // through the store and next iteration's VALU phase.
        const int nn = (n + 1 < NCH) ? n + 1 : NCH - 1;   // tail: reload last
        pf = img_v[(rowpix + nn * CHUNK) * 4 + tix];
        float d_next = depth[rowpix + nn * CHUNK + pl];

        f32x4 r;
        r.x = g00.x * w00 + g01.x * w01 + g10.x * w10 + g11.x * w11;
        r.y = g00.y * w00 + g01.y * w01 + g10.y * w10 + g11.y * w11;
        r.z = g00.z * w00 + g01.z * w01 + g10.z * w10 + g11.z * w11;
        r.w = g00.w * w00 + g01.w * w01 + g10.w * w10 + g11.w * w11;

        // write-once stream: nontemporal so stores don't evict warm image
        __builtin_nontemporal_store(r, out_v + (rowpix + px) * 4 + c4);

        d_cur = d_next;
    }
}

extern "C" void kernel_launch(void* const* d_in, const int* in_sizes, int n_in,
                              void* d_out, int out_size, void* d_ws, size_t ws_size,
                              hipStream_t stream) {
    const float* image = (const float*)d_in[0];
    const float* depth = (const float*)d_in[1];
    const float* proj  = (const float*)d_in[2];
    float4* out = (float4*)d_out;

    depth_project_kernel<<<GRID, BLOCK, 0, stream>>>(image, depth, proj, out);
}